// Round 3
// baseline (369.202 us; speedup 1.0000x reference)
//
#include <hip/hip_runtime.h>

#define NB 64
#define NDIM 512
#define NNE (NDIM * NDIM)      // 262144
#define NR 40
#define NL 20
#define SUBS 16                // blocks per batch
#define ITERS 16               // iterations per thread, 4 elems each
#define NCOL 128               // rider bin columns (2 threads share one column)
#define NROW (NR + 1)          // +1 dummy row for invalid ids (branchless)

// ws layout (floats):
//   PART: NB*SUBS blocks x 64 floats:
//     [0..3]=tat, 4=dmd_time, 5=unserved, 6=tot_dem, 7=n_disc, 8=n_edges,
//     9=max_drive, [10..49]=riders
//   RT_OFF: NB x 4: 0=total_route_time, 1=n_routes_used, 2=n_stops_oob
//   FLAG_OFF: 1 int (has_path layout: 1 = byte, 0 = int32)
#define PART_STRIDE 64
#define NPART (NB * SUBS)
#define RT_OFF (NPART * PART_STRIDE)
#define FLAG_OFF (RT_OFF + NB * 4)

struct Acc {
    float t0, t1, t2, t3, dmdt, uns, tdem, ndisc, nedge, maxd;
};

__global__ void detect_kernel(const unsigned int* __restrict__ hp, int* __restrict__ flag) {
    unsigned int v = hp[threadIdx.x];
    unsigned long long m = __ballot(v > 1u);
    if (threadIdx.x == 0) *flag = (m != 0ull) ? 1 : 0;
}

__device__ __forceinline__ void proc4(float4 dem4, float4 tt4, float4 dt4, int4 nt4,
                                      int h0, int h1, int h2, int h3,
                                      int4 r0, int4 r1, int4 r2, int4 r3,
                                      Acc& a, float* __restrict__ bins, int col)
{
    const float dems[4] = {dem4.x, dem4.y, dem4.z, dem4.w};
    const float tts[4]  = {tt4.x,  tt4.y,  tt4.z,  tt4.w};
    const float dts[4]  = {dt4.x,  dt4.y,  dt4.z,  dt4.w};
    const int   nts[4]  = {nt4.x,  nt4.y,  nt4.z,  nt4.w};
    const int   hs[4]   = {h0, h1, h2, h3};
    const int rsa[16] = {r0.x, r0.y, r0.z, r0.w, r1.x, r1.y, r1.z, r1.w,
                         r2.x, r2.y, r2.z, r2.w, r3.x, r3.y, r3.z, r3.w};
#pragma unroll
    for (int e = 0; e < 4; ++e) {
        const float d = dems[e];
        const bool np_ = (hs[e] == 0);
        const int nte = np_ ? 3 : nts[e];
        a.t0 += (nte == 0) ? d : 0.0f;
        a.t1 += (nte == 1) ? d : 0.0f;
        a.t2 += (nte == 2) ? d : 0.0f;
        a.t3 += (nte > 2) ? d : 0.0f;
        a.dmdt += np_ ? 0.0f : d * tts[e];
        a.uns  += np_ ? d : 0.0f;
        a.tdem += d;
        a.maxd = fmaxf(a.maxd, dts[e]);
        const bool pos = d > 0.0f;
        a.ndisc += (np_ && pos) ? 1.0f : 0.0f;
        a.nedge += pos ? 1.0f : 0.0f;
#pragma unroll
        for (int k = 0; k < 4; ++k) {
            const int id = rsa[e * 4 + k];
            const int row = ((unsigned)id < (unsigned)NR) ? id : NR;  // -1 -> dummy
            atomicAdd(&bins[row * NCOL + col], d);
        }
    }
}

template<bool BYTE>
__device__ __forceinline__ void mainloop(
    const float* __restrict__ pd, const float* __restrict__ pt,
    const float* __restrict__ pdr, const int* __restrict__ pn,
    const unsigned char* __restrict__ phb, const int* __restrict__ phw,
    const int* __restrict__ prs, Acc& a, float* __restrict__ bins, int col)
{
#pragma unroll 1
    for (int it = 0; it < ITERS; it += 2) {
        const int oA = it * 1024;
        const int oB = oA + 1024;

        // ---- issue ALL loads for two iterations before consuming any ----
        const float4 demA = *(const float4*)(pd + oA);
        const float4 demB = *(const float4*)(pd + oB);
        const float4 ttA  = *(const float4*)(pt + oA);
        const float4 ttB  = *(const float4*)(pt + oB);
        const float4 dtA  = *(const float4*)(pdr + oA);
        const float4 dtB  = *(const float4*)(pdr + oB);
        const int4   ntA  = *(const int4*)(pn + oA);
        const int4   ntB  = *(const int4*)(pn + oB);
        const int4 rA0 = *(const int4*)(prs + oA * 4);
        const int4 rA1 = *(const int4*)(prs + oA * 4 + 4);
        const int4 rA2 = *(const int4*)(prs + oA * 4 + 8);
        const int4 rA3 = *(const int4*)(prs + oA * 4 + 12);
        const int4 rB0 = *(const int4*)(prs + oB * 4);
        const int4 rB1 = *(const int4*)(prs + oB * 4 + 4);
        const int4 rB2 = *(const int4*)(prs + oB * 4 + 8);
        const int4 rB3 = *(const int4*)(prs + oB * 4 + 12);
        int hA0, hA1, hA2, hA3, hB0, hB1, hB2, hB3;
        if (BYTE) {
            const uchar4 hA = *(const uchar4*)(phb + oA);
            const uchar4 hB = *(const uchar4*)(phb + oB);
            hA0 = hA.x; hA1 = hA.y; hA2 = hA.z; hA3 = hA.w;
            hB0 = hB.x; hB1 = hB.y; hB2 = hB.z; hB3 = hB.w;
        } else {
            const int4 hA = *(const int4*)(phw + oA);
            const int4 hB = *(const int4*)(phw + oB);
            hA0 = hA.x; hA1 = hA.y; hA2 = hA.z; hA3 = hA.w;
            hB0 = hB.x; hB1 = hB.y; hB2 = hB.z; hB3 = hB.w;
        }

        proc4(demA, ttA, dtA, ntA, hA0, hA1, hA2, hA3, rA0, rA1, rA2, rA3, a, bins, col);
        proc4(demB, ttB, dtB, ntB, hB0, hB1, hB2, hB3, rB0, rB1, rB2, rB3, a, bins, col);
    }
}

__global__ __launch_bounds__(256, 4) void main_kernel(
    const float* __restrict__ demand,
    const float* __restrict__ transit,
    const unsigned char* __restrict__ hp_raw,
    const float* __restrict__ drive,
    const int* __restrict__ ntr,
    const int* __restrict__ rseq,
    const int* __restrict__ flag,
    float* __restrict__ ws)
{
    __shared__ float bins[NROW * NCOL];   // 41*128*4 = 21 KB
    __shared__ float red[4][10];
    const int tid = threadIdx.x;
    const int wave = tid >> 6;
    const int lane = tid & 63;
    const int col = tid >> 1;

    for (int i = tid; i < NROW * NCOL; i += 256) bins[i] = 0.0f;
    __syncthreads();

    const int b = blockIdx.x >> 4;
    const int sub = blockIdx.x & 15;
    const size_t base0 = (size_t)b * NNE + (size_t)sub * (NNE / SUBS);
    const size_t e0 = base0 + (size_t)tid * 4;

    Acc a = {0, 0, 0, 0, 0, 0, 0, 0, 0, 0};

    if (*flag != 0) {
        mainloop<true>(demand + e0, transit + e0, drive + e0, ntr + e0,
                       hp_raw + e0, nullptr, rseq + e0 * 4, a, bins, col);
    } else {
        mainloop<false>(demand + e0, transit + e0, drive + e0, ntr + e0,
                        nullptr, ((const int*)hp_raw) + e0, rseq + e0 * 4, a, bins, col);
    }
    __syncthreads();   // bins complete

#pragma unroll
    for (int o = 32; o > 0; o >>= 1) {
        a.t0 += __shfl_down(a.t0, o);
        a.t1 += __shfl_down(a.t1, o);
        a.t2 += __shfl_down(a.t2, o);
        a.t3 += __shfl_down(a.t3, o);
        a.dmdt += __shfl_down(a.dmdt, o);
        a.uns  += __shfl_down(a.uns, o);
        a.tdem += __shfl_down(a.tdem, o);
        a.ndisc += __shfl_down(a.ndisc, o);
        a.nedge += __shfl_down(a.nedge, o);
        a.maxd = fmaxf(a.maxd, __shfl_down(a.maxd, o));
    }
    if (lane == 0) {
        red[wave][0] = a.t0; red[wave][1] = a.t1; red[wave][2] = a.t2; red[wave][3] = a.t3;
        red[wave][4] = a.dmdt; red[wave][5] = a.uns;  red[wave][6] = a.tdem;
        red[wave][7] = a.ndisc; red[wave][8] = a.nedge; red[wave][9] = a.maxd;
    }
    __syncthreads();

    float* part = ws + (size_t)blockIdx.x * PART_STRIDE;
    if (tid < 10) {
        if (tid == 9) {
            part[9] = fmaxf(fmaxf(red[0][9], red[1][9]), fmaxf(red[2][9], red[3][9]));
        } else {
            part[tid] = red[0][tid] + red[1][tid] + red[2][tid] + red[3][tid];
        }
    }

    // tree-reduce rider bins over columns
#pragma unroll
    for (int sh = 6; sh >= 0; --sh) {
        const int s = 1 << sh;
        for (int i = tid; i < (NR << sh); i += 256) {
            const int r = i >> sh, t = i & (s - 1);
            bins[r * NCOL + t] += bins[r * NCOL + t + s];
        }
        __syncthreads();
    }
    if (tid < NR) part[10 + tid] = bins[tid * NCOL];
}

__global__ __launch_bounds__(64) void route_kernel(
    const int* __restrict__ routes,
    const float* __restrict__ drive,
    float* __restrict__ ws)
{
    const int b = blockIdx.x;
    const int r = threadIdx.x;
    float t = 0.0f, used = 0.0f, oob = 0.0f;
    if (r < NR) {
        const int* rt = routes + (b * NR + r) * NL;
        int v[NL];
        int len = 0;
#pragma unroll
        for (int l = 0; l < NL; ++l) { v[l] = rt[l]; len += (v[l] > -1) ? 1 : 0; }
        const float* D = drive + (size_t)b * NNE;
#pragma unroll
        for (int l = 0; l < NL - 1; ++l) {
            int f = v[l], to = v[l + 1];
            if (f >= 0 && to >= 0)
                t += D[f * NDIM + to] + D[to * NDIM + f] + 120.0f;  // 60s each direction
        }
        used = (len > 0) ? 1.0f : 0.0f;
        int delta = 2 - len;
        oob = (len > 0 && delta > 0) ? (float)delta : 0.0f;
    }
#pragma unroll
    for (int o = 32; o > 0; o >>= 1) {
        t += __shfl_down(t, o);
        used += __shfl_down(used, o);
        oob += __shfl_down(oob, o);
    }
    if (r == 0) {
        float* a = ws + RT_OFF + b * 4;
        a[0] = t; a[1] = used; a[2] = oob;
    }
}

__global__ __launch_bounds__(64) void final_kernel(const float* __restrict__ ws,
                                                   float* __restrict__ out) {
    __shared__ float fin[50];
    const int b = blockIdx.x;
    const int v = threadIdx.x;
    if (v < 50) {
        const float* p = ws + (size_t)b * SUBS * PART_STRIDE + v;
        float a = p[0];
#pragma unroll
        for (int s = 1; s < SUBS; ++s) {
            const float x = p[(size_t)s * PART_STRIDE];
            a = (v == 9) ? fmaxf(a, x) : (a + x);
        }
        fin[v] = a;
    }
    __syncthreads();
    if (v == 0) {
        const float* rt = ws + RT_OFF + b * 4;
        const float trt = rt[0], nru = rt[1], noob = rt[2];
        const float dmdt = fin[4], uns = fin[5], tdem = fin[6];
        const float ndisc = fin[7], nedge = fin[8], tn = fin[9];
        const float served = tdem - uns;
        const float cost = 0.5f * ((dmdt / (served + 1e-6f)) / tn)
                         + 0.5f * (trt / (tn * nru + 1e-6f))
                         + 5.0f * (ndisc / nedge + noob / (nru * 2.0f + 1e-6f));
        out[b] = cost;
        out[64 + NB * NR + NB * 4 + b] = trt;
    }
    if (v < 4) out[64 + NB * NR + b * 4 + v] = fin[v];
    if (v >= 10 && v < 50) out[64 + b * NR + (v - 10)] = fin[v];
}

extern "C" void kernel_launch(void* const* d_in, const int* in_sizes, int n_in,
                              void* d_out, int out_size, void* d_ws, size_t ws_size,
                              hipStream_t stream) {
    const float* demand  = (const float*)d_in[0];
    const float* drive   = (const float*)d_in[1];
    const float* transit = (const float*)d_in[2];
    const unsigned char* hp = (const unsigned char*)d_in[3];
    const int* ntr    = (const int*)d_in[4];
    const int* routes = (const int*)d_in[5];
    const int* rseq   = (const int*)d_in[6];
    float* out = (float*)d_out;
    float* ws  = (float*)d_ws;
    int* flag  = (int*)(ws + FLAG_OFF);

    detect_kernel<<<1, 64, 0, stream>>>((const unsigned int*)hp, flag);
    route_kernel<<<NB, 64, 0, stream>>>(routes, drive, ws);
    main_kernel<<<NB * SUBS, 256, 0, stream>>>(demand, transit, hp, drive, ntr, rseq, flag, ws);
    final_kernel<<<NB, 64, 0, stream>>>(ws, out);
}